// Round 2
// baseline (146.459 us; speedup 1.0000x reference)
//
#include <hip/hip_runtime.h>
#include <hip/hip_bf16.h>
#include <cstdint>
#include <cstddef>
#include <math.h>

// Problem constants (reference: B=4096, D=256, T=0.5)
#define BSZ   4096
#define NROW  8192          // 2*B
#define DIM   256
#define INV_T 2.0f
#define EPS_N 1e-8f

typedef __attribute__((ext_vector_type(8))) short bf16x8;   // 8 bf16 = 4 VGPRs
typedef __attribute__((ext_vector_type(4))) float f32x4;

__device__ __forceinline__ unsigned short f2bf(float x) {
    __hip_bfloat16 h = __float2bfloat16(x);
    return __builtin_bit_cast(unsigned short, h);
}

// ---------------------------------------------------------------------------
// Kernel 1: row-normalize concat(z1,z2), fp32 math, bf16 out. One row/wave,
// float4 loads (16B/lane), no block barriers. Also zeroes rowsum[row].
__global__ __launch_bounds__(256)
void nt_normalize(const float* __restrict__ z1,
                  const float* __restrict__ z2,
                  __hip_bfloat16* __restrict__ zn,
                  float* __restrict__ rowsum) {
    const int wave = threadIdx.x >> 6;
    const int lane = threadIdx.x & 63;
    const int row  = blockIdx.x * 4 + wave;
    const float* src = (row < BSZ) ? (z1 + (size_t)row * DIM)
                                   : (z2 + (size_t)(row - BSZ) * DIM);
    const float4 v = ((const float4*)src)[lane];
    float ss = v.x * v.x + v.y * v.y + v.z * v.z + v.w * v.w;
    #pragma unroll
    for (int off = 32; off; off >>= 1) ss += __shfl_xor(ss, off);
    const float rinv = 1.0f / fmaxf(sqrtf(ss), EPS_N);  // torch eps clamp
    ushort4 o;
    o.x = f2bf(v.x * rinv);
    o.y = f2bf(v.y * rinv);
    o.z = f2bf(v.z * rinv);
    o.w = f2bf(v.w * rinv);
    ((ushort4*)(zn + (size_t)row * DIM))[lane] = o;
    if (lane == 0) rowsum[row] = 0.0f;
}

// ---------------------------------------------------------------------------
// Kernel 2: tiled Zn·Znᵀ, upper triangle, 128x128 tiles (2080 blocks), 256
// threads = 4 waves in a 2x2 grid (64x64 output per wave).
//
// Theory-of-change vs rounds 0/1 (both ~46-49 us, MfmaUtil ~13%): those were
// latency-exposed on LDS staging (vmcnt(0) drain at every barrier, 1-2
// blocks/CU). zn is 4 MB = one XCD's L2, so staging is pointless: read MFMA
// fragments DIRECTLY from global (L2-hit) into registers, register
// double-buffered, ZERO barriers in the K-loop. No LDS for operands ->
// ~150 VGPR, 3 waves/SIMD, ~8 block-rounds of TLP to hide L2 latency.
// Fragment pattern: 16 rows x 64 B contiguous; consecutive kk steps consume
// full 128 B lines. Total L2 read ~532 MB -> ~15 us floor at 36 TB/s.
__global__ __launch_bounds__(256)
void nt_gram(const __hip_bfloat16* __restrict__ zn,
             float* __restrict__ rowsum,
             float* __restrict__ pos) {
    // XCD-contiguous remap (2080 = 8*260, bijective), then triangular decode.
    const int bid = blockIdx.x;
    const int l = (bid & 7) * 260 + (bid >> 3);
    int bi = (int)((129.0 - sqrt(16641.0 - 8.0 * (double)l)) * 0.5);
    while (64 * (bi + 1) - (bi + 1) * bi / 2 <= l) ++bi;   // fp-edge correction
    while (64 * bi - bi * (bi - 1) / 2 > l) --bi;
    const int bj = bi + (l - (64 * bi - bi * (bi - 1) / 2));

    const int t    = threadIdx.x;
    const int lane = t & 63;
    const int wave = t >> 6;
    const int wrow = (wave >> 1) * 64;
    const int wcol = (wave & 1) * 64;
    const int q    = lane >> 4;
    const int r16  = lane & 15;

    // Per-lane fragment base pointers (byte addressing; row = 512 B).
    // Fragment (mi, kb): 16 rows (r16) x 16 B chunk (q) at K-byte kb.
    const char* pa = (const char*)zn + ((size_t)bi * 128 + wrow + r16) * 512 + q * 16;
    const char* pb = (const char*)zn + ((size_t)bj * 128 + wcol + r16) * 512 + q * 16;

    f32x4 acc[4][4] = {};
    bf16x8 a0[4], b0[4], a1[4], b1[4];

    auto LOADF = [&](bf16x8* A, bf16x8* B, int kb) {
        #pragma unroll
        for (int mi = 0; mi < 4; ++mi)
            A[mi] = *(const bf16x8*)(pa + mi * 8192 + kb);
        #pragma unroll
        for (int ni = 0; ni < 4; ++ni)
            B[ni] = *(const bf16x8*)(pb + ni * 8192 + kb);
    };
    auto MF = [&](bf16x8* A, bf16x8* B) {
        #pragma unroll
        for (int mi = 0; mi < 4; ++mi)
            #pragma unroll
            for (int ni = 0; ni < 4; ++ni)
                acc[mi][ni] = __builtin_amdgcn_mfma_f32_16x16x32_bf16(
                    A[mi], B[ni], acc[mi][ni], 0, 0, 0);
    };

    // K-loop: DIM=256 -> 8 sub-steps of K=32 (64 B), reg ping-pong, no barriers.
    LOADF(a0, b0, 0);
    int kb = 64;
    #pragma unroll 1
    for (int it = 0; it < 3; ++it) {
        LOADF(a1, b1, kb);        // prefetch next while a0/b0 compute
        MF(a0, b0);
        LOADF(a0, b0, kb + 64);
        MF(a1, b1);
        kb += 128;
    }
    LOADF(a1, b1, 448);           // last sub-step (no OOB prefetch)
    MF(a0, b0);
    MF(a1, b1);

    // Epilogue: LDS reduce (1 KB) then one global atomic per row/col.
    __shared__ float red[256];    // rowacc[128] | colacc[128]
    red[t] = 0.0f;
    __syncthreads();
    float* rowacc = red;
    float* colacc = red + 128;

    // C/D layout: col=lane&15, row=(lane>>4)*4+reg (m89-verified).
    const int  c          = r16;
    const bool diag_block = (bi == bj);
    float colp[4] = {0.f, 0.f, 0.f, 0.f};

    #pragma unroll
    for (int mi = 0; mi < 4; ++mi) {
        #pragma unroll
        for (int r = 0; r < 4; ++r) {
            const int trow = wrow + mi * 16 + q * 4 + r;
            const int grow = bi * 128 + trow;
            float s = 0.f;
            #pragma unroll
            for (int ni = 0; ni < 4; ++ni) {
                const int gcol = bj * 128 + wcol + ni * 16 + c;
                const float val = acc[mi][ni][r];
                float e = __expf(val * INV_T);
                e = (grow == gcol) ? 0.f : e;   // exact diagonal exclusion
                s += e;
                colp[ni] += e;
                if (gcol == grow + BSZ) {       // positive pair (bj == bi+32)
                    pos[grow] = val;
                    pos[gcol] = val;            // symmetric partner
                }
            }
            s += __shfl_xor(s, 1);
            s += __shfl_xor(s, 2);
            s += __shfl_xor(s, 4);
            s += __shfl_xor(s, 8);
            if (c == 0) atomicAdd(&rowacc[trow], s);   // LDS ds_add
        }
    }
    if (!diag_block) {   // diag tiles: col sums would double-count (symmetry)
        #pragma unroll
        for (int ni = 0; ni < 4; ++ni) {
            float cs = colp[ni];
            cs += __shfl_xor(cs, 16);
            cs += __shfl_xor(cs, 32);
            if (q == 0) atomicAdd(&colacc[wcol + ni * 16 + c], cs);  // LDS
        }
    }
    __syncthreads();
    if (t < 128) {
        atomicAdd(&rowsum[bi * 128 + t], rowacc[t]);
    } else if (!diag_block) {
        atomicAdd(&rowsum[bj * 128 + (t - 128)], colacc[t - 128]);
    }
}

// ---------------------------------------------------------------------------
// Kernel 3: single block, 1024 threads; writes out[0] directly.
__global__ __launch_bounds__(1024)
void nt_finalize(const float* __restrict__ rowsum,
                 const float* __restrict__ pos,
                 float* __restrict__ out) {
    float v = 0.f;
    for (int i = threadIdx.x; i < NROW; i += 1024) {
        const float pl = pos[i] * INV_T;
        v += logf(__expf(pl) + rowsum[i]) - pl;
    }
    #pragma unroll
    for (int off = 32; off; off >>= 1) v += __shfl_xor(v, off);
    __shared__ float red[16];
    if ((threadIdx.x & 63) == 0) red[threadIdx.x >> 6] = v;
    __syncthreads();
    if (threadIdx.x == 0) {
        float s = 0.f;
        #pragma unroll
        for (int w = 0; w < 16; ++w) s += red[w];
        out[0] = s * (1.0f / NROW);
    }
}

// ---------------------------------------------------------------------------
extern "C" void kernel_launch(void* const* d_in, const int* in_sizes, int n_in,
                              void* d_out, int out_size, void* d_ws, size_t ws_size,
                              hipStream_t stream) {
    const float* z1 = (const float*)d_in[0];
    const float* z2 = (const float*)d_in[1];
    float* out = (float*)d_out;

    __hip_bfloat16* zn = (__hip_bfloat16*)d_ws;                       // 4 MB
    float* rowsum = (float*)((char*)d_ws + (size_t)NROW * DIM * 2);   // 32 KB
    float* pos    = rowsum + NROW;                                    // 32 KB

    nt_normalize<<<NROW / 4, 256, 0, stream>>>(z1, z2, zn, rowsum);
    nt_gram<<<2080, 256, 0, stream>>>(zn, rowsum, pos);
    nt_finalize<<<1, 1024, 0, stream>>>(rowsum, pos, out);
}

// Round 3
// 108.199 us; speedup vs baseline: 1.3536x; 1.3536x over previous
//
#include <hip/hip_runtime.h>
#include <hip/hip_bf16.h>
#include <cstdint>
#include <cstddef>
#include <math.h>

// Problem constants (reference: B=4096, D=256, T=0.5)
#define BSZ   4096
#define NROW  8192          // 2*B
#define DIM   256
#define INV_T 2.0f
#define EPS_N 1e-8f

typedef __attribute__((ext_vector_type(8))) short bf16x8;   // 8 bf16 = 4 VGPRs
typedef __attribute__((ext_vector_type(4))) float f32x4;

__device__ __forceinline__ unsigned short f2bf(float x) {
    __hip_bfloat16 h = __float2bfloat16(x);
    return __builtin_bit_cast(unsigned short, h);
}

// async global->LDS 16B helper (wave-uniform LDS base + lane*16 layout)
__device__ __forceinline__ void load_lds16(const void* g, void* l) {
    __builtin_amdgcn_global_load_lds(
        (const __attribute__((address_space(1))) void*)g,
        (__attribute__((address_space(3))) void*)l,
        16, 0, 0);
}

#define VMWAIT(N) asm volatile("s_waitcnt vmcnt(" #N ")" ::: "memory")

// ---------------------------------------------------------------------------
// Kernel 1: row-normalize concat(z1,z2), fp32 math, bf16 out. One row/wave,
// float4 loads (16B/lane), no block barriers. Also zeroes rowsum[row].
__global__ __launch_bounds__(256)
void nt_normalize(const float* __restrict__ z1,
                  const float* __restrict__ z2,
                  __hip_bfloat16* __restrict__ zn,
                  float* __restrict__ rowsum) {
    const int wave = threadIdx.x >> 6;
    const int lane = threadIdx.x & 63;
    const int row  = blockIdx.x * 4 + wave;
    const float* src = (row < BSZ) ? (z1 + (size_t)row * DIM)
                                   : (z2 + (size_t)(row - BSZ) * DIM);
    const float4 v = ((const float4*)src)[lane];
    float ss = v.x * v.x + v.y * v.y + v.z * v.z + v.w * v.w;
    #pragma unroll
    for (int off = 32; off; off >>= 1) ss += __shfl_xor(ss, off);
    const float rinv = 1.0f / fmaxf(sqrtf(ss), EPS_N);  // torch eps clamp
    ushort4 o;
    o.x = f2bf(v.x * rinv);
    o.y = f2bf(v.y * rinv);
    o.z = f2bf(v.z * rinv);
    o.w = f2bf(v.w * rinv);
    ((ushort4*)(zn + (size_t)row * DIM))[lane] = o;
    if (lane == 0) rowsum[row] = 0.0f;
}

// ---------------------------------------------------------------------------
// Kernel 2: tiled Zn·Znᵀ, upper triangle, 128x128 tiles (2080 blocks), 256
// threads = 4 waves (2x2 grid of 64x64 wave-tiles).
//
// Theory-of-change vs R0-R2 (all ~10 B/cyc/CU effective staging = outstanding
// limited against cold-L2 / L3-latency reads):
//  (a) 8x8 SUPERTILE tile order: tiles grouped so any run of ~64 consecutive
//      l touches only 8 A-strips + 8 B-strips = 1 MB << 4 MB L2 (no LRU
//      sweep-thrash, unlike R2's 4 MB sweeps).
//  (b) XCD-contiguous runs (l = (bid&7)*260 + bid>>3, 2080=8*260, bijective):
//      each XCD walks ~4 overlapping 1 MB footprints -> staging becomes
//      L2-hit (~300cy) instead of L3 (~1.5-2k cy).
//  (c) Counted-vmcnt double-buffer (raw s_barrier + vmcnt(8), never 0 in
//      the loop): 16 loads/wave in flight, no full drain per K-step.
//  (d) LDS epilogue reduction (verified R1/R2): 512 global atomics/block -> 256.
__global__ __launch_bounds__(256)
void nt_gram(const __hip_bfloat16* __restrict__ zn,
             float* __restrict__ rowsum,
             float* __restrict__ pos) {
    __shared__ char ldsbuf[65536];          // A0|B0|A1|B1, 16 KB each
    __shared__ float red[256];              // rowacc[128] | colacc[128]

    // --- supertile decode (upper-tri 64x64 strips, 8x8 supertiles) --------
    // Order: 8 diagonal supertiles (36 tiles each, 0..287), then 28 strict
    // upper supertiles (64 tiles each, 288..2079). Row-major inside.
    const int bid = blockIdx.x;
    const int l = (bid & 7) * 260 + (bid >> 3);   // XCD-contiguous, bijective
    int bi, bj;
    if (l < 288) {
        const int S = l / 36;                // diag supertile index
        const int u = l - S * 36;            // 0..35, upper-tri 8x8 incl diag
        int i = 0, off = 0;
        while (u >= off + (8 - i)) { off += 8 - i; ++i; }
        const int j = i + (u - off);
        bi = 8 * S + i;
        bj = 8 * S + j;
    } else {
        const int m = (l - 288) >> 6;        // 0..27 strict upper 8x8 pairs
        const int u = (l - 288) & 63;
        int I = 0, off = 0;
        while (m >= off + (7 - I)) { off += 7 - I; ++I; }
        const int J = I + 1 + (m - off);
        bi = 8 * I + (u >> 3);
        bj = 8 * J + (u & 7);
    }

    const int t    = threadIdx.x;
    const int lane = t & 63;
    const int wave = t >> 6;
    const int wrow = (wave >> 1) * 64;
    const int wcol = (wave & 1) * 64;
    const int q    = lane >> 4;
    const int r16  = lane & 15;

    char* A0 = ldsbuf;
    char* B0 = ldsbuf + 16384;
    char* A1 = ldsbuf + 32768;
    char* B1 = ldsbuf + 49152;

    const __hip_bfloat16* Ag = zn + (size_t)bi * 128 * DIM;
    const __hip_bfloat16* Bg = zn + (size_t)bj * 128 * DIM;

    const int srow = t >> 3;                 // 0..31 per pass
    const int sc   = (t & 7) ^ (srow & 7);   // pre-swizzled global chunk
    const int sw   = r16 & 7;                // read-side swizzle key

    f32x4 acc[4][4] = {};

    auto STAGE = [&](int k0, char* As, char* Bs) {
        #pragma unroll
        for (int p = 0; p < 4; ++p) {
            const int row = p * 32 + srow;   // row&7 == srow&7, pass-invariant
            load_lds16(Ag + (size_t)row * DIM + k0 + sc * 8, As + p * 4096 + t * 16);
            load_lds16(Bg + (size_t)row * DIM + k0 + sc * 8, Bs + p * 4096 + t * 16);
        }
    };

    auto COMPUTE = [&](const char* As, const char* Bs) {
        #pragma unroll
        for (int kk = 0; kk < 64; kk += 32) {
            const int cc   = (kk >> 3) + q;       // chunk index within row
            const int cpos = (cc ^ sw) << 4;      // swizzled byte position
            bf16x8 af[4], bfr[4];
            #pragma unroll
            for (int mi = 0; mi < 4; ++mi)
                af[mi] = *(const bf16x8*)(As + (wrow + mi * 16 + r16) * 128 + cpos);
            #pragma unroll
            for (int ni = 0; ni < 4; ++ni)
                bfr[ni] = *(const bf16x8*)(Bs + (wcol + ni * 16 + r16) * 128 + cpos);
            #pragma unroll
            for (int mi = 0; mi < 4; ++mi)
                #pragma unroll
                for (int ni = 0; ni < 4; ++ni)
                    acc[mi][ni] = __builtin_amdgcn_mfma_f32_16x16x32_bf16(
                        af[mi], bfr[ni], acc[mi][ni], 0, 0, 0);
        }
    };

    // K pipeline: 4 steps of BK=64, double-buffered, counted vmcnt.
    // Each STAGE = 8 load_lds16 per wave; vmcnt(8) waits the older stage only.
    STAGE(0, A0, B0);
    STAGE(64, A1, B1);
    VMWAIT(8);
    __builtin_amdgcn_s_barrier();
    COMPUTE(A0, B0);
    __builtin_amdgcn_s_barrier();            // all waves done reading buf0
    STAGE(128, A0, B0);
    VMWAIT(8);
    __builtin_amdgcn_s_barrier();
    COMPUTE(A1, B1);
    __builtin_amdgcn_s_barrier();            // all waves done reading buf1
    STAGE(192, A1, B1);
    VMWAIT(8);
    __builtin_amdgcn_s_barrier();
    COMPUTE(A0, B0);
    VMWAIT(0);
    __builtin_amdgcn_s_barrier();
    COMPUTE(A1, B1);

    // Epilogue: zero LDS accumulators, then ds_add reduce, then one global
    // atomic per row/col. (__syncthreads here is safe: nothing outstanding.)
    red[t] = 0.0f;
    __syncthreads();
    float* rowacc = red;
    float* colacc = red + 128;

    // C/D layout: col=lane&15, row=(lane>>4)*4+reg (m89-verified).
    const int  c          = r16;
    const bool diag_block = (bi == bj);
    float colp[4] = {0.f, 0.f, 0.f, 0.f};

    #pragma unroll
    for (int mi = 0; mi < 4; ++mi) {
        #pragma unroll
        for (int r = 0; r < 4; ++r) {
            const int trow = wrow + mi * 16 + q * 4 + r;
            const int grow = bi * 128 + trow;
            float s = 0.f;
            #pragma unroll
            for (int ni = 0; ni < 4; ++ni) {
                const int gcol = bj * 128 + wcol + ni * 16 + c;
                const float val = acc[mi][ni][r];
                float e = __expf(val * INV_T);
                e = (grow == gcol) ? 0.f : e;   // exact diagonal exclusion
                s += e;
                colp[ni] += e;
                if (gcol == grow + BSZ) {       // positive pair (bj == bi+32)
                    pos[grow] = val;
                    pos[gcol] = val;            // symmetric partner
                }
            }
            s += __shfl_xor(s, 1);
            s += __shfl_xor(s, 2);
            s += __shfl_xor(s, 4);
            s += __shfl_xor(s, 8);
            if (c == 0) atomicAdd(&rowacc[trow], s);   // LDS ds_add
        }
    }
    if (!diag_block) {   // diag tiles: col sums would double-count (symmetry)
        #pragma unroll
        for (int ni = 0; ni < 4; ++ni) {
            float cs = colp[ni];
            cs += __shfl_xor(cs, 16);
            cs += __shfl_xor(cs, 32);
            if (q == 0) atomicAdd(&colacc[wcol + ni * 16 + c], cs);  // LDS
        }
    }
    __syncthreads();
    if (t < 128) {
        atomicAdd(&rowsum[bi * 128 + t], rowacc[t]);
    } else if (!diag_block) {
        atomicAdd(&rowsum[bj * 128 + (t - 128)], colacc[t - 128]);
    }
}

// ---------------------------------------------------------------------------
// Kernel 3: single block, 1024 threads; writes out[0] directly.
__global__ __launch_bounds__(1024)
void nt_finalize(const float* __restrict__ rowsum,
                 const float* __restrict__ pos,
                 float* __restrict__ out) {
    float v = 0.f;
    for (int i = threadIdx.x; i < NROW; i += 1024) {
        const float pl = pos[i] * INV_T;
        v += logf(__expf(pl) + rowsum[i]) - pl;
    }
    #pragma unroll
    for (int off = 32; off; off >>= 1) v += __shfl_xor(v, off);
    __shared__ float redf[16];
    if ((threadIdx.x & 63) == 0) redf[threadIdx.x >> 6] = v;
    __syncthreads();
    if (threadIdx.x == 0) {
        float s = 0.f;
        #pragma unroll
        for (int w = 0; w < 16; ++w) s += redf[w];
        out[0] = s * (1.0f / NROW);
    }
}

// ---------------------------------------------------------------------------
extern "C" void kernel_launch(void* const* d_in, const int* in_sizes, int n_in,
                              void* d_out, int out_size, void* d_ws, size_t ws_size,
                              hipStream_t stream) {
    const float* z1 = (const float*)d_in[0];
    const float* z2 = (const float*)d_in[1];
    float* out = (float*)d_out;

    __hip_bfloat16* zn = (__hip_bfloat16*)d_ws;                       // 4 MB
    float* rowsum = (float*)((char*)d_ws + (size_t)NROW * DIM * 2);   // 32 KB
    float* pos    = rowsum + NROW;                                    // 32 KB

    nt_normalize<<<NROW / 4, 256, 0, stream>>>(z1, z2, zn, rowsum);
    nt_gram<<<2080, 256, 0, stream>>>(zn, rowsum, pos);
    nt_finalize<<<1, 1024, 0, stream>>>(rowsum, pos, out);
}

// Round 5
// 107.236 us; speedup vs baseline: 1.3658x; 1.0090x over previous
//
#include <hip/hip_runtime.h>
#include <hip/hip_bf16.h>
#include <cstdint>
#include <cstddef>
#include <math.h>

// Problem constants (reference: B=4096, D=256, T=0.5)
#define BSZ   4096
#define NROW  8192          // 2*B
#define DIM   256
#define INV_T 2.0f
#define EPS_N 1e-8f

typedef __attribute__((ext_vector_type(8))) short bf16x8;   // 8 bf16 = 4 VGPRs
typedef __attribute__((ext_vector_type(4))) float f32x4;

__device__ __forceinline__ unsigned short f2bf(float x) {
    __hip_bfloat16 h = __float2bfloat16(x);
    return __builtin_bit_cast(unsigned short, h);
}

// async global->LDS 16B helper (wave-uniform LDS base + lane*16 layout)
__device__ __forceinline__ void load_lds16(const void* g, void* l) {
    __builtin_amdgcn_global_load_lds(
        (const __attribute__((address_space(1))) void*)g,
        (__attribute__((address_space(3))) void*)l,
        16, 0, 0);
}

// ---------------------------------------------------------------------------
// zn2 staged layout (the experiment): [strip(64)][kc(4)][row(128)][unit16(8)],
// XOR-swizzle BAKED IN at write time:
//   zn2[s][kc][row][u] = znorm[s*128+row] bytes kc*128 + (u^(row&7))*16 .. +16
// Gram's global_load_lds source for (strip, kc) is then ONE contiguous 16 KB
// sequential stream (prefetch/MSHR-friendly: consecutive lanes -> consecutive
// lines), while the LDS image stays bit-identical to the verified R0 layout.
//
// Kernel 1: row-normalize concat(z1,z2) into zn2. One row/wave, float4 loads,
// no block barriers. Also zeroes rowsum[row].
__global__ __launch_bounds__(256)
void nt_normalize(const float* __restrict__ z1,
                  const float* __restrict__ z2,
                  char* __restrict__ zn2,
                  float* __restrict__ rowsum) {
    const int wave = threadIdx.x >> 6;
    const int lane = threadIdx.x & 63;
    const int row  = blockIdx.x * 4 + wave;
    const float* src = (row < BSZ) ? (z1 + (size_t)row * DIM)
                                   : (z2 + (size_t)(row - BSZ) * DIM);
    const float4 v = ((const float4*)src)[lane];
    float ss = v.x * v.x + v.y * v.y + v.z * v.z + v.w * v.w;
    #pragma unroll
    for (int off = 32; off; off >>= 1) ss += __shfl_xor(ss, off);
    const float rinv = 1.0f / fmaxf(sqrtf(ss), EPS_N);  // torch eps clamp
    ushort4 o;
    o.x = f2bf(v.x * rinv);
    o.y = f2bf(v.y * rinv);
    o.z = f2bf(v.z * rinv);
    o.w = f2bf(v.w * rinv);
    // lane i holds row bytes [8i, 8i+8): kc=i>>4, unit=(i>>1)&7, half=i&1
    const int s    = row >> 7;
    const int lrow = row & 127;
    const int kc   = lane >> 4;
    const int unit = (lane >> 1) & 7;
    const int half = lane & 1;
    const int u    = unit ^ (lrow & 7);          // baked swizzle
    *(ushort4*)(zn2 + (size_t)s * 65536 + kc * 16384 + lrow * 128 + u * 16 + half * 8) = o;
    if (lane == 0) rowsum[row] = 0.0f;
}

// ---------------------------------------------------------------------------
// Kernel 2: tiled Zn·Znᵀ, upper triangle only (1D triangular grid, 2080
// blocks). EXACT R0 structure (proven best, 46 us): single-buffered 32 KB
// LDS, plain __syncthreads, 5 blocks/CU, plain pos stores, global atomics.
// ONLY change: staging source is the contiguous zn2 layout.
__global__ __launch_bounds__(256)
void nt_gram(const char* __restrict__ zn2,
             float* __restrict__ rowsum,
             float* __restrict__ pos) {
    // Triangular decode: S(bi) = 64*bi - bi*(bi-1)/2 tiles before row bi.
    const int l = blockIdx.x;
    int bi = (int)((129.0 - sqrt(16641.0 - 8.0 * (double)l)) * 0.5);
    while (64 * (bi + 1) - (bi + 1) * bi / 2 <= l) ++bi;   // fp-edge correction
    while (64 * bi - bi * (bi - 1) / 2 > l) --bi;
    const int bj = bi + (l - (64 * bi - bi * (bi - 1) / 2));

    __shared__ char As[16384];   // [128 rows][128 B], swizzled image
    __shared__ char Bs[16384];

    const int t    = threadIdx.x;
    const int lane = t & 63;
    const int wave = t >> 6;
    const int wrow = (wave >> 1) * 64;
    const int wcol = (wave & 1) * 64;
    const int q    = lane >> 4;
    const int r16  = lane & 15;
    const int sw   = r16 & 7;                    // read-side swizzle key

    const char* A2 = zn2 + (size_t)bi * 65536;
    const char* B2 = zn2 + (size_t)bj * 65536;

    f32x4 acc[4][4] = {};

    for (int kc = 0; kc < 4; ++kc) {
        // Contiguous staging: two pure 16 KB sequential streams.
        #pragma unroll
        for (int p = 0; p < 4; ++p)
            load_lds16(A2 + kc * 16384 + p * 4096 + t * 16, As + p * 4096 + t * 16);
        #pragma unroll
        for (int p = 0; p < 4; ++p)
            load_lds16(B2 + kc * 16384 + p * 4096 + t * 16, Bs + p * 4096 + t * 16);
        __syncthreads();

        #pragma unroll
        for (int kk = 0; kk < 64; kk += 32) {
            const int cc   = (kk >> 3) + q;       // chunk index within row
            const int cpos = (cc ^ sw) << 4;      // swizzled byte position
            bf16x8 af[4], bfr[4];
            #pragma unroll
            for (int mi = 0; mi < 4; ++mi)
                af[mi] = *(const bf16x8*)(As + (wrow + mi * 16 + r16) * 128 + cpos);
            #pragma unroll
            for (int ni = 0; ni < 4; ++ni)
                bfr[ni] = *(const bf16x8*)(Bs + (wcol + ni * 16 + r16) * 128 + cpos);
            #pragma unroll
            for (int mi = 0; mi < 4; ++mi)
                #pragma unroll
                for (int ni = 0; ni < 4; ++ni)
                    acc[mi][ni] = __builtin_amdgcn_mfma_f32_16x16x32_bf16(
                        af[mi], bfr[ni], acc[mi][ni], 0, 0, 0);
        }
        __syncthreads();
    }

    // Epilogue (R0-exact). C/D layout: col=lane&15, row=(lane>>4)*4+reg.
    const int c = r16;
    const bool diag_block = (bi == bj);
    float colp[4] = {0.f, 0.f, 0.f, 0.f};

    #pragma unroll
    for (int mi = 0; mi < 4; ++mi) {
        #pragma unroll
        for (int r = 0; r < 4; ++r) {
            const int grow = bi * 128 + wrow + mi * 16 + q * 4 + r;
            float s = 0.f;
            #pragma unroll
            for (int ni = 0; ni < 4; ++ni) {
                const int gcol = bj * 128 + wcol + ni * 16 + c;
                const float val = acc[mi][ni][r];
                float e = __expf(val * INV_T);
                e = (grow == gcol) ? 0.f : e;   // exact diagonal exclusion
                s += e;
                colp[ni] += e;
                if (gcol == grow + BSZ) {       // positive pair (bj == bi+32)
                    pos[grow] = val;
                    pos[gcol] = val;            // symmetric partner
                }
            }
            s += __shfl_xor(s, 1);
            s += __shfl_xor(s, 2);
            s += __shfl_xor(s, 4);
            s += __shfl_xor(s, 8);
            if (c == 0) atomicAdd(&rowsum[grow], s);
        }
    }
    // Column sums -> bj strip rows (symmetry); skip on diagonal tiles.
    if (!diag_block) {
        #pragma unroll
        for (int ni = 0; ni < 4; ++ni) {
            float cs = colp[ni];
            cs += __shfl_xor(cs, 16);
            cs += __shfl_xor(cs, 32);
            if (q == 0) atomicAdd(&rowsum[bj * 128 + wcol + ni * 16 + c], cs);
        }
    }
}

// ---------------------------------------------------------------------------
// Kernel 3: single block, 1024 threads; writes out[0] directly.
__global__ __launch_bounds__(1024)
void nt_finalize(const float* __restrict__ rowsum,
                 const float* __restrict__ pos,
                 float* __restrict__ out) {
    float v = 0.f;
    for (int i = threadIdx.x; i < NROW; i += 1024) {
        const float pl = pos[i] * INV_T;
        v += logf(__expf(pl) + rowsum[i]) - pl;
    }
    #pragma unroll
    for (int off = 32; off; off >>= 1) v += __shfl_xor(v, off);
    __shared__ float red[16];
    if ((threadIdx.x & 63) == 0) red[threadIdx.x >> 6] = v;
    __syncthreads();
    if (threadIdx.x == 0) {
        float s = 0.f;
        #pragma unroll
        for (int w = 0; w < 16; ++w) s += red[w];
        out[0] = s * (1.0f / NROW);
    }
}

// ---------------------------------------------------------------------------
extern "C" void kernel_launch(void* const* d_in, const int* in_sizes, int n_in,
                              void* d_out, int out_size, void* d_ws, size_t ws_size,
                              hipStream_t stream) {
    const float* z1 = (const float*)d_in[0];
    const float* z2 = (const float*)d_in[1];
    float* out = (float*)d_out;

    char*  zn2    = (char*)d_ws;                                      // 4 MB
    float* rowsum = (float*)((char*)d_ws + (size_t)NROW * DIM * 2);   // 32 KB
    float* pos    = rowsum + NROW;                                    // 32 KB

    nt_normalize<<<NROW / 4, 256, 0, stream>>>(z1, z2, zn2, rowsum);
    nt_gram<<<2080, 256, 0, stream>>>(zn2, rowsum, pos);
    nt_finalize<<<1, 1024, 0, stream>>>(rowsum, pos, out);
}

// Round 6
// 105.937 us; speedup vs baseline: 1.3825x; 1.0123x over previous
//
#include <hip/hip_runtime.h>
#include <hip/hip_bf16.h>
#include <cstdint>
#include <cstddef>
#include <math.h>

// Problem constants (reference: B=4096, D=256, T=0.5)
#define BSZ   4096
#define NROW  8192          // 2*B
#define DIM   256
#define INV_T 2.0f
#define EPS_N 1e-8f
#define NTILE 528           // 32 strips of 256 rows, upper triangle

typedef __attribute__((ext_vector_type(8))) short bf16x8;   // 8 bf16 = 4 VGPRs
typedef __attribute__((ext_vector_type(4))) float f32x4;

__device__ __forceinline__ unsigned short f2bf(float x) {
    __hip_bfloat16 h = __float2bfloat16(x);
    return __builtin_bit_cast(unsigned short, h);
}

// async global->LDS 16B helper (wave-uniform LDS base + lane*16 layout)
__device__ __forceinline__ void load_lds16(const void* g, void* l) {
    __builtin_amdgcn_global_load_lds(
        (const __attribute__((address_space(1))) void*)g,
        (__attribute__((address_space(3))) void*)l,
        16, 0, 0);
}

// ---------------------------------------------------------------------------
// zn2 staged layout (R5-verified mechanism, restriped for 256-row strips):
// [strip(32)][kc(4)][row(256)][unit16(8)], XOR-swizzle baked in:
//   zn2[s][kc][row][u] holds row bytes kc*128 + (u^(row&7))*16 .. +16
// => gram staging is pure sequential 16 KB streams; LDS image = verified
// swizzled layout; read side identical to R0/R5.
//
// Kernel 1: row-normalize concat(z1,z2) into zn2. One row/wave. Also zeroes
// rowsum[row].
__global__ __launch_bounds__(256)
void nt_normalize(const float* __restrict__ z1,
                  const float* __restrict__ z2,
                  char* __restrict__ zn2,
                  float* __restrict__ rowsum) {
    const int wave = threadIdx.x >> 6;
    const int lane = threadIdx.x & 63;
    const int row  = blockIdx.x * 4 + wave;
    const float* src = (row < BSZ) ? (z1 + (size_t)row * DIM)
                                   : (z2 + (size_t)(row - BSZ) * DIM);
    const float4 v = ((const float4*)src)[lane];
    float ss = v.x * v.x + v.y * v.y + v.z * v.z + v.w * v.w;
    #pragma unroll
    for (int off = 32; off; off >>= 1) ss += __shfl_xor(ss, off);
    const float rinv = 1.0f / fmaxf(sqrtf(ss), EPS_N);  // torch eps clamp
    ushort4 o;
    o.x = f2bf(v.x * rinv);
    o.y = f2bf(v.y * rinv);
    o.z = f2bf(v.z * rinv);
    o.w = f2bf(v.w * rinv);
    // lane i holds row bytes [8i, 8i+8): kc=i>>4, unit=(i>>1)&7, half=i&1
    const int s    = row >> 8;
    const int lrow = row & 255;
    const int kc   = lane >> 4;
    const int unit = (lane >> 1) & 7;
    const int half = lane & 1;
    const int u    = unit ^ (lrow & 7);          // baked swizzle
    *(ushort4*)(zn2 + (size_t)s * 131072 + kc * 32768 + lrow * 128 + u * 16 + half * 8) = o;
    if (lane == 0) rowsum[row] = 0.0f;
}

// ---------------------------------------------------------------------------
// Kernel 2: tiled Zn·Znᵀ, upper triangle, 256x256 tiles (528 blocks), 1024
// threads = 16 waves (4x4 grid of 64x64 wave-tiles; acc stays at 64 VGPR so
// 4 waves/SIMD fit — unlike R1's 8-wave/190-VGPR version).
//
// Theory-of-change (T3/T4 from the catalog): fully-counted vmcnt pipeline —
// loads for K-tiles t+1, t+2 stay in flight ACROSS the per-K-tile barriers,
// never draining to 0 mid-loop (ledger: 4,4,4,0). Every prior round drained
// (10 B/cyc/CU plateau); counted-vmcnt structures measure ~21-24 B/cyc.
// Combined with 256² halving staged bytes to 135 MB.
__global__ __launch_bounds__(1024)
void nt_gram(const char* __restrict__ zn2,
             float* __restrict__ rowsum,
             float* __restrict__ pos) {
    __shared__ char  ldsbuf[131072];   // buf0: A|B (32K+32K), buf1: A|B
    __shared__ float red[512];         // rowacc[256] | colacc[256]

    // XCD-contiguous remap (528 = 8*66, bijective), then triangular decode
    // over 32 strips: S(bi) = 32*bi - bi*(bi-1)/2 tiles precede row bi.
    const int bid = blockIdx.x;
    const int l = (bid & 7) * 66 + (bid >> 3);
    int bi = (int)((65.0 - sqrt(4225.0 - 8.0 * (double)l)) * 0.5);
    while (32 * (bi + 1) - (bi + 1) * bi / 2 <= l) ++bi;   // fp-edge correction
    while (32 * bi - bi * (bi - 1) / 2 > l) --bi;
    const int bj = bi + (l - (32 * bi - bi * (bi - 1) / 2));

    const int t    = threadIdx.x;
    const int lane = t & 63;
    const int wave = t >> 6;
    const int wrow = (wave >> 2) * 64;   // 0,64,128,192
    const int wcol = (wave & 3) * 64;    // 0,64,128,192
    const int q    = lane >> 4;
    const int r16  = lane & 15;
    const int sw   = r16 & 7;            // read-side swizzle key
    const int t16  = t * 16;

    const char* Asrc = zn2 + (size_t)bi * 131072;
    const char* Bsrc = zn2 + (size_t)bj * 131072;

    f32x4 acc[4][4] = {};

    // Stage K-tile kc into dbuf: 4 global_load_lds per wave (A.l0,A.l1,B.l0,B.l1),
    // each line = 1024 threads x 16 B = 16 KB, pure sequential source.
#define STAGE(kc, dbuf)                                                      \
    {                                                                        \
        const char* as_ = Asrc + (kc) * 32768;                               \
        const char* bs_ = Bsrc + (kc) * 32768;                               \
        char* ad_ = ldsbuf + (dbuf) * 65536;                                 \
        char* bd_ = ad_ + 32768;                                             \
        load_lds16(as_ + t16,         ad_ + t16);                            \
        load_lds16(as_ + 16384 + t16, ad_ + 16384 + t16);                    \
        load_lds16(bs_ + t16,         bd_ + t16);                            \
        load_lds16(bs_ + 16384 + t16, bd_ + 16384 + t16);                    \
    }

    // One K-tile compute: reads its dbuf (As [256][128B] swizzled image).
#define KHALF(As_, Bs_, kk)                                                  \
    {                                                                        \
        const int cpos = ((((kk) >> 3) + q) ^ sw) << 4;                      \
        bf16x8 af[4], bfv[4];                                                \
        _Pragma("unroll")                                                    \
        for (int mi = 0; mi < 4; ++mi)                                       \
            af[mi] = *(const bf16x8*)((As_) + (wrow + mi * 16 + r16) * 128 + cpos); \
        _Pragma("unroll")                                                    \
        for (int ni = 0; ni < 4; ++ni)                                       \
            bfv[ni] = *(const bf16x8*)((Bs_) + (wcol + ni * 16 + r16) * 128 + cpos); \
        __builtin_amdgcn_s_setprio(1);                                       \
        _Pragma("unroll")                                                    \
        for (int mi = 0; mi < 4; ++mi)                                       \
            _Pragma("unroll")                                                \
            for (int ni = 0; ni < 4; ++ni)                                   \
                acc[mi][ni] = __builtin_amdgcn_mfma_f32_16x16x32_bf16(       \
                    af[mi], bfv[ni], acc[mi][ni], 0, 0, 0);                  \
        __builtin_amdgcn_s_setprio(0);                                       \
    }

    // K-step: wait this tile's 4 loads (counted: N = loads still allowed in
    // flight), barrier, compute both kk halves, barrier, then (optionally)
    // stage K-tile t+2 into the just-consumed buffer.
#define K_STEP(nwait, dbuf, do_stage, kc_stage)                              \
    {                                                                        \
        asm volatile("s_waitcnt vmcnt(" #nwait ")" ::: "memory");            \
        __builtin_amdgcn_s_barrier();                                        \
        const char* As_ = ldsbuf + (dbuf) * 65536;                           \
        const char* Bs_ = As_ + 32768;                                       \
        KHALF(As_, Bs_, 0)                                                   \
        KHALF(As_, Bs_, 32)                                                  \
        __builtin_amdgcn_s_barrier();                                        \
        __builtin_amdgcn_sched_barrier(0);                                   \
        if (do_stage) STAGE(kc_stage, dbuf)                                  \
    }

    // Pipeline: ledger of outstanding per-wave loads: 8 -> wait4 -> 8 ->
    // wait4 -> 8 -> wait4 -> 4 -> wait0. Never drains mid-loop (T4).
    STAGE(0, 0)
    STAGE(1, 1)
    K_STEP(4, 0, 1, 2)
    K_STEP(4, 1, 1, 3)
    K_STEP(4, 0, 0, 0)
    K_STEP(0, 1, 0, 0)

    // Epilogue: LDS reduce then one global atomic per row/col per block.
    if (t < 512) red[t] = 0.0f;
    __syncthreads();
    float* rowacc = red;
    float* colacc = red + 256;

    // C/D layout: col=lane&15, row=(lane>>4)*4+reg (m89-verified).
    const int  c          = r16;
    const bool diag_block = (bi == bj);
    float colp[4] = {0.f, 0.f, 0.f, 0.f};

    #pragma unroll
    for (int mi = 0; mi < 4; ++mi) {
        #pragma unroll
        for (int r = 0; r < 4; ++r) {
            const int trow = wrow + mi * 16 + q * 4 + r;
            const int grow = bi * 256 + trow;
            float s = 0.f;
            #pragma unroll
            for (int ni = 0; ni < 4; ++ni) {
                const int gcol = bj * 256 + wcol + ni * 16 + c;
                const float val = acc[mi][ni][r];
                float e = __expf(val * INV_T);
                e = (grow == gcol) ? 0.f : e;   // exact diagonal exclusion
                s += e;
                colp[ni] += e;
                if (gcol == grow + BSZ) {       // positive pair (bj == bi+16)
                    pos[grow] = val;
                    pos[gcol] = val;            // symmetric partner
                }
            }
            s += __shfl_xor(s, 1);
            s += __shfl_xor(s, 2);
            s += __shfl_xor(s, 4);
            s += __shfl_xor(s, 8);
            if (c == 0) atomicAdd(&rowacc[trow], s);   // LDS ds_add
        }
    }
    if (!diag_block) {   // diag tiles: col sums would double-count (symmetry)
        #pragma unroll
        for (int ni = 0; ni < 4; ++ni) {
            float cs = colp[ni];
            cs += __shfl_xor(cs, 16);
            cs += __shfl_xor(cs, 32);
            if (q == 0) atomicAdd(&colacc[wcol + ni * 16 + c], cs);  // LDS
        }
    }
    __syncthreads();
    if (t < 256) {
        atomicAdd(&rowsum[bi * 256 + t], rowacc[t]);
    } else if (t < 512 && !diag_block) {
        atomicAdd(&rowsum[bj * 256 + (t - 256)], colacc[t - 256]);
    }
#undef STAGE
#undef KHALF
#undef K_STEP
}

// ---------------------------------------------------------------------------
// Kernel 3: single block, 1024 threads; writes out[0] directly.
__global__ __launch_bounds__(1024)
void nt_finalize(const float* __restrict__ rowsum,
                 const float* __restrict__ pos,
                 float* __restrict__ out) {
    float v = 0.f;
    for (int i = threadIdx.x; i < NROW; i += 1024) {
        const float pl = pos[i] * INV_T;
        v += logf(__expf(pl) + rowsum[i]) - pl;
    }
    #pragma unroll
    for (int off = 32; off; off >>= 1) v += __shfl_xor(v, off);
    __shared__ float redf[16];
    if ((threadIdx.x & 63) == 0) redf[threadIdx.x >> 6] = v;
    __syncthreads();
    if (threadIdx.x == 0) {
        float s = 0.f;
        #pragma unroll
        for (int w = 0; w < 16; ++w) s += redf[w];
        out[0] = s * (1.0f / NROW);
    }
}

// ---------------------------------------------------------------------------
extern "C" void kernel_launch(void* const* d_in, const int* in_sizes, int n_in,
                              void* d_out, int out_size, void* d_ws, size_t ws_size,
                              hipStream_t stream) {
    const float* z1 = (const float*)d_in[0];
    const float* z2 = (const float*)d_in[1];
    float* out = (float*)d_out;

    char*  zn2    = (char*)d_ws;                                      // 4 MB
    float* rowsum = (float*)((char*)d_ws + (size_t)NROW * DIM * 2);   // 32 KB
    float* pos    = rowsum + NROW;                                    // 32 KB

    nt_normalize<<<NROW / 4, 256, 0, stream>>>(z1, z2, zn2, rowsum);
    nt_gram<<<NTILE, 1024, 0, stream>>>(zn2, rowsum, pos);
    nt_finalize<<<1, 1024, 0, stream>>>(rowsum, pos, out);
}